// Round 13
// baseline (57.710 us; speedup 1.0000x reference)
//
#include <hip/hip_runtime.h>
#include <stdint.h>
#include <math.h>

#define BB 4
#define HH 512
#define WW 512
#define HWW (HH*WW)      // 262144
#define CC 128
#define KK 512
#define SELCAP 2048
#define NBIN 8192
#define NPADK 512

#define TILE 64
#define HALO 15
#define TS 94
#define SWL 104
#define NT 1024
#define TCAP 512
#define NW2 16

typedef unsigned int uint;
typedef unsigned long long u64;

__device__ __forceinline__ float4 ldsf4(const float* p, int o){ return *(const float4*)(p + o); }
__device__ __forceinline__ float4 f4max(float4 a, float4 b){
    return make_float4(fmaxf(a.x,b.x), fmaxf(a.y,b.y), fmaxf(a.z,b.z), fmaxf(a.w,b.w));
}

// ---- row passes: horizontal register sliding (A,B,C), runs of 8 groups ----
// dst[o] = 7-wide row max; reads each src value ~once (1.25 loads/output).
#define ROWMAX_RUN(dst, src, Y0, NROW, G0, NG)                                \
    { const int RUNS = ((NG) + 7) / 8;                                        \
      for (int th = tid; th < (NROW)*RUNS; th += NT){                         \
        int row = th / RUNS, u = th % RUNS;                                   \
        int y = (Y0) + row, g0 = u*8;                                         \
        int o0 = y*SWL + (G0) + 4*g0 + 4;                                     \
        float4 Ax = ldsf4(src, o0-4), Bx = ldsf4(src, o0);                    \
        _Pragma("unroll")                                                     \
        for (int q = 0; q < 8; ++q){                                          \
            if (g0 + q < (NG)){                                               \
                int o = o0 + 4*q;                                             \
                float4 Cx = ldsf4(src, o+4);                                  \
                float m2a=fmaxf(Ax.y,Ax.z), m2b=fmaxf(Ax.w,Bx.x),             \
                      m2c=fmaxf(Bx.y,Bx.z), m2d=fmaxf(Bx.w,Cx.x),             \
                      m2e=fmaxf(Cx.y,Cx.z);                                   \
                float4 r;                                                     \
                r.x = fmaxf(fmaxf(m2a,m2b), fmaxf(m2c, Bx.w));                \
                r.y = fmaxf(fmaxf(Ax.z,m2b), fmaxf(m2c, m2d));                \
                r.z = fmaxf(fmaxf(m2b,m2c), fmaxf(m2d, Cx.y));                \
                r.w = fmaxf(fmaxf(Bx.x,m2c), fmaxf(m2d, m2e));                \
                *(float4*)((dst) + o) = r;                                    \
                Ax = Bx; Bx = Cx;                                             \
            }                                                                 \
        }                                                                     \
      }                                                                       \
    }                                                                         \
    __syncthreads();

#define ROWOR_RUN(dst, src, Y0, NROW, G0, NG)                                 \
    { const int RUNS = ((NG) + 7) / 8;                                        \
      for (int th = tid; th < (NROW)*RUNS; th += NT){                         \
        int row = th / RUNS, u = th % RUNS;                                   \
        int y = (Y0) + row, g0 = u*8;                                         \
        int o0 = y*SWL + (G0) + 4*g0 + 4;                                     \
        uint Au = *(const uint*)((src)+o0-4), Bu = *(const uint*)((src)+o0);  \
        _Pragma("unroll")                                                     \
        for (int q = 0; q < 8; ++q){                                          \
            if (g0 + q < (NG)){                                               \
                int o = o0 + 4*q;                                             \
                uint Cu = *(const uint*)((src)+o+4);                          \
                u64 lo = (u64)Au | ((u64)Bu << 32);                           \
                uint r = (uint)(lo>>8) | (uint)(lo>>16) | (uint)(lo>>24)      \
                       | (uint)(lo>>32) | ((uint)(lo>>40)|(Cu<<24))           \
                       | ((uint)(lo>>48)|(Cu<<16)) | ((uint)(lo>>56)|(Cu<<8));\
                *(uint*)((dst)+o) = r;                                        \
                Au = Bu; Bu = Cu;                                             \
            }                                                                 \
        }                                                                     \
      }                                                                       \
    }                                                                         \
    __syncthreads();

// ---- column passes: vertical register ring (w0..w6), strips of H rows ----
// Full unroll => ring shift is register renaming (no VALU, no scratch).

// One block = one 64x64 tile (+15 halo). 2-iteration NMS fully in LDS.
__global__ __launch_bounds__(NT) void nms_fused_k(const float* __restrict__ sc,
        float* __restrict__ cs, int* __restrict__ ci, int* __restrict__ cnt){
    __shared__ __align__(16) float S[TS*SWL];
    __shared__ __align__(16) float A[TS*SWL];
    __shared__ __align__(16) float Bf[TS*SWL];
    __shared__ __align__(16) unsigned char M[TS*SWL];
    __shared__ __align__(16) unsigned char T[TS*SWL];
    __shared__ __align__(16) unsigned char P[TS*SWL];
    __shared__ float lsc[TCAP];
    __shared__ int   lidx[TCAP];
    __shared__ int   lcnt;

    const int tid = threadIdx.x;
    const int bb = blockIdx.x >> 6;
    const int t  = blockIdx.x & 63;
    const int ty = t >> 3, tx = t & 7;
    const int oy = ty * TILE - HALO, ox = tx * TILE - HALO;
    const float* sb = sc + (size_t)bb * HWW;
    const float QNAN = __int_as_float(0x7fc00000);

    if (tid == 0) lcnt = 0;

    for (int i = tid; i < TS*SWL; i += NT){
        int y = i / SWL, x = i - y*SWL;
        int gy = oy + y, gx = ox + x - 4;
        float v = QNAN;
        if ((unsigned)gy < (unsigned)HH && (unsigned)gx < (unsigned)WW)
            v = sb[(gy << 9) + gx];
        S[i] = v;
    }
    __syncthreads();

    // 1. rowmax S -> A  (rows [0,94), NG 23, G0 0)
    ROWMAX_RUN(A, S, 0, 94, 0, 23)

    // 2. colmax(A) + M0  (y [3,91), NG 23, G0 0, H=8, 11 strips)
    for (int th = tid; th < 11*23; th += NT){
        int st = th / 23, g = th % 23;
        int ys = 3 + st*8;
        int xo = 4*g + 4;
        float4 w0 = ldsf4(A,(ys-3)*SWL+xo), w1 = ldsf4(A,(ys-2)*SWL+xo),
               w2 = ldsf4(A,(ys-1)*SWL+xo), w3 = ldsf4(A,(ys  )*SWL+xo),
               w4 = ldsf4(A,(ys+1)*SWL+xo), w5 = ldsf4(A,(ys+2)*SWL+xo);
        #pragma unroll
        for (int r2 = 0; r2 < 8; ++r2){
            int y = ys + r2;
            float4 w6 = ldsf4(A,(y+3)*SWL+xo);
            float4 cm = f4max(f4max(f4max(w0,w1),f4max(w2,w3)), f4max(f4max(w4,w5),w6));
            float4 s4 = ldsf4(S, y*SWL+xo);
            uint m = (s4.x==cm.x?1u:0u)|(s4.y==cm.y?0x100u:0u)
                   | (s4.z==cm.z?0x10000u:0u)|(s4.w==cm.w?0x1000000u:0u);
            *(uint*)(M + y*SWL+xo) = m;
            w0=w1; w1=w2; w2=w3; w3=w4; w4=w5; w5=w6;
        }
    }
    __syncthreads();

    // 3. row-OR M -> T  (y [3,91), NG 21, G0 4)
    ROWOR_RUN(T, M, 3, 88, 4, 21)

    // 4. col-OR(T) -> P; A = supp?0:S  (y [6,88), NG 21, G0 4, H=6, 14 strips)
    for (int th = tid; th < 14*21; th += NT){
        int st = th / 21, g = th % 21;
        int ys = 6 + st*6;
        int xo = 4*g + 8;
        uint t0 = *(uint*)(T+(ys-3)*SWL+xo), t1 = *(uint*)(T+(ys-2)*SWL+xo),
             t2 = *(uint*)(T+(ys-1)*SWL+xo), t3 = *(uint*)(T+(ys  )*SWL+xo),
             t4 = *(uint*)(T+(ys+1)*SWL+xo), t5 = *(uint*)(T+(ys+2)*SWL+xo);
        #pragma unroll
        for (int r2 = 0; r2 < 6; ++r2){
            int y = ys + r2;
            if (y < 88){
                uint t6 = *(uint*)(T+(y+3)*SWL+xo);
                uint v = t0|t1|t2|t3|t4|t5|t6;
                *(uint*)(P + y*SWL+xo) = v;
                float4 s4 = ldsf4(S, y*SWL+xo);
                float4 a;
                a.x = (v & 0xffu)       ? 0.0f : s4.x;
                a.y = (v & 0xff00u)     ? 0.0f : s4.y;
                a.z = (v & 0xff0000u)   ? 0.0f : s4.z;
                a.w = (v & 0xff000000u) ? 0.0f : s4.w;
                *(float4*)(A + y*SWL+xo) = a;
                t0=t1; t1=t2; t2=t3; t3=t4; t4=t5; t5=t6;
            }
        }
    }
    __syncthreads();

    // 5. rowmax A -> Bf  (y [6,88), NG 20, G0 8)
    ROWMAX_RUN(Bf, A, 6, 82, 8, 20)

    // 6. colmax(Bf): M |= (ss==cm) & ~P  (y [9,85), NG 20, G0 8, H=4, 19 strips)
    for (int th = tid; th < 19*20; th += NT){
        int st = th / 20, g = th % 20;
        int ys = 9 + st*4;
        int xo = 4*g + 12;
        float4 w0 = ldsf4(Bf,(ys-3)*SWL+xo), w1 = ldsf4(Bf,(ys-2)*SWL+xo),
               w2 = ldsf4(Bf,(ys-1)*SWL+xo), w3 = ldsf4(Bf,(ys  )*SWL+xo),
               w4 = ldsf4(Bf,(ys+1)*SWL+xo), w5 = ldsf4(Bf,(ys+2)*SWL+xo);
        #pragma unroll
        for (int r2 = 0; r2 < 4; ++r2){
            int y = ys + r2;
            float4 w6 = ldsf4(Bf,(y+3)*SWL+xo);
            float4 cm = f4max(f4max(f4max(w0,w1),f4max(w2,w3)), f4max(f4max(w4,w5),w6));
            float4 a4 = ldsf4(A, y*SWL+xo);
            uint p4 = *(uint*)(P + y*SWL+xo);
            uint nm = (a4.x==cm.x?1u:0u)|(a4.y==cm.y?0x100u:0u)
                    | (a4.z==cm.z?0x10000u:0u)|(a4.w==cm.w?0x1000000u:0u);
            uint m4 = *(uint*)(M + y*SWL+xo);
            *(uint*)(M + y*SWL+xo) = m4 | (nm & ~p4);
            w0=w1; w1=w2; w2=w3; w3=w4; w4=w5; w5=w6;
        }
    }
    __syncthreads();

    // 7. row-OR M -> T  (y [9,85), NG 18, G0 12)
    ROWOR_RUN(T, M, 9, 76, 12, 18)

    // 8. col-OR(T) -> P; A = supp?0:S  (y [12,82), NG 18, G0 12, H=7, 10 strips)
    for (int th = tid; th < 10*18; th += NT){
        int st = th / 18, g = th % 18;
        int ys = 12 + st*7;
        int xo = 4*g + 16;
        uint t0 = *(uint*)(T+(ys-3)*SWL+xo), t1 = *(uint*)(T+(ys-2)*SWL+xo),
             t2 = *(uint*)(T+(ys-1)*SWL+xo), t3 = *(uint*)(T+(ys  )*SWL+xo),
             t4 = *(uint*)(T+(ys+1)*SWL+xo), t5 = *(uint*)(T+(ys+2)*SWL+xo);
        #pragma unroll
        for (int r2 = 0; r2 < 7; ++r2){
            int y = ys + r2;
            if (y < 82){
                uint t6 = *(uint*)(T+(y+3)*SWL+xo);
                uint v = t0|t1|t2|t3|t4|t5|t6;
                *(uint*)(P + y*SWL+xo) = v;
                float4 s4 = ldsf4(S, y*SWL+xo);
                float4 a;
                a.x = (v & 0xffu)       ? 0.0f : s4.x;
                a.y = (v & 0xff00u)     ? 0.0f : s4.y;
                a.z = (v & 0xff0000u)   ? 0.0f : s4.z;
                a.w = (v & 0xff000000u) ? 0.0f : s4.w;
                *(float4*)(A + y*SWL+xo) = a;
                t0=t1; t1=t2; t2=t3; t3=t4; t4=t5; t5=t6;
            }
        }
    }
    __syncthreads();

    // 9. rowmax A -> Bf  (y [12,82), NG 17, G0 12)
    ROWMAX_RUN(Bf, A, 12, 70, 12, 17)

    // 10. colmax(Bf) + final mask + compact  (y [15,79), NG 17, G0 12, H=8, 8 strips)
    for (int th = tid; th < 8*17; th += NT){
        int st = th / 17, g = th % 17;
        int ys = 15 + st*8;
        int xo = 4*g + 16;              // lds-x; image x = xo - 4 + j
        float4 w0 = ldsf4(Bf,(ys-3)*SWL+xo), w1 = ldsf4(Bf,(ys-2)*SWL+xo),
               w2 = ldsf4(Bf,(ys-1)*SWL+xo), w3 = ldsf4(Bf,(ys  )*SWL+xo),
               w4 = ldsf4(Bf,(ys+1)*SWL+xo), w5 = ldsf4(Bf,(ys+2)*SWL+xo);
        #pragma unroll
        for (int r2 = 0; r2 < 8; ++r2){
            int y = ys + r2;
            float4 w6 = ldsf4(Bf,(y+3)*SWL+xo);
            float4 cm = f4max(f4max(f4max(w0,w1),f4max(w2,w3)), f4max(f4max(w4,w5),w6));
            float4 a4 = ldsf4(A, y*SWL+xo), s4 = ldsf4(S, y*SWL+xo);
            uint p4 = *(uint*)(P + y*SWL+xo), m4 = *(uint*)(M + y*SWL+xo);
            float sa[4] = {s4.x, s4.y, s4.z, s4.w};
            float aa[4] = {a4.x, a4.y, a4.z, a4.w};
            float ca[4] = {cm.x, cm.y, cm.z, cm.w};
            #pragma unroll
            for (int j = 0; j < 4; ++j){
                int x = xo - 4 + j;
                bool fm = ((m4 >> (8*j)) & 1u) || ((aa[j]==ca[j]) && !((p4 >> (8*j)) & 1u));
                if ((unsigned)(x - 15) < 64u && fm && sa[j] > 0.0f){
                    int p = atomicAdd(&lcnt, 1);
                    if (p < TCAP){ lsc[p] = sa[j]; lidx[p] = ((oy+y) << 9) + (ox+x); }
                }
            }
            w0=w1; w1=w2; w2=w3; w3=w4; w4=w5; w5=w6;
        }
    }
    __syncthreads();

    int nl = lcnt; if (nl > TCAP) nl = TCAP;
    const int seg = bb * 64 + t;
    if (tid == 0) cnt[seg] = nl;
    float* os = cs + (size_t)seg * TCAP;
    int*   oi = ci + (size_t)seg * TCAP;
    for (int i = tid; i < nl; i += NT){ os[i] = lsc[i]; oi[i] = lidx[i]; }
}

// ---------- fused select+gather v3 (byte-identical to round 12) ----------

__device__ __forceinline__ uint fxbin(float v){
    return ((uint)(v * 8388608.0f)) >> 10;
}

__global__ __launch_bounds__(NT) void selgather_k(
        const float* __restrict__ cs, const int* __restrict__ ci, const int* __restrict__ cnt,
        const float* __restrict__ pts, const float* __restrict__ feat,
        float* __restrict__ out){
    __shared__ int  hist[NBIN];
    __shared__ __align__(16) u64 keys[SELCAP + 4];
    __shared__ int  segc[64];
    __shared__ int  wsum[16];
    __shared__ int  sidx[KK];
    __shared__ uint sh_Tbits;
    __shared__ int  sh_bin, sh_kneed, sh_n, selCnt, bcnt;

    const int blk = blockIdx.x;
    const int b = blk >> 6, slice = blk & 63;
    const int tid = threadIdx.x;
    const int wv = tid >> 6, lane = tid & 63;

    {
        int4* h4 = (int4*)hist;
        for (int i = tid; i < NBIN/4; i += NT) h4[i] = make_int4(0,0,0,0);
    }
    if (tid < 64){ int c = cnt[b*64 + tid]; segc[tid] = (c > TCAP) ? TCAP : c; }
    if (tid == 0){ selCnt = 0; bcnt = 0; sh_Tbits = 1u; }
    __syncthreads();

    #pragma unroll
    for (int ss = 0; ss < 4; ++ss){
        int s = wv*4 + ss;
        int c = segc[s];
        const float* ps = cs + (size_t)(b*64 + s) * TCAP;
        for (int i = lane; i < c; i += 64)
            atomicAdd(&hist[fxbin(ps[i])], 1);
    }
    __syncthreads();

    int hh[8];
    {
        int4 h0 = *(int4*)&hist[tid*8], h1 = *(int4*)&hist[tid*8 + 4];
        hh[0]=h0.x; hh[1]=h0.y; hh[2]=h0.z; hh[3]=h0.w;
        hh[4]=h1.x; hh[5]=h1.y; hh[6]=h1.z; hh[7]=h1.w;
    }
    int s8 = hh[0]+hh[1]+hh[2]+hh[3]+hh[4]+hh[5]+hh[6]+hh[7];
    int suf = s8;
    #pragma unroll
    for (int off = 1; off < 64; off <<= 1){
        int v = __shfl_down(suf, off);
        if (lane + off < 64) suf += v;
    }
    if (lane == 0) wsum[wv] = suf;
    __syncthreads();
    int W = 0, tot = 0;
    #pragma unroll
    for (int w2 = 0; w2 < 16; ++w2){ int v = wsum[w2]; tot += v; if (w2 > wv) W += v; }
    if (tid == 0) sh_n = tot;
    int G = W + (suf - s8);
    if (tot >= KK && G < KK && G + s8 >= KK){
        int cum = G;
        #pragma unroll
        for (int k = 7; k >= 0; --k){
            if (cum + hh[k] >= KK){ sh_bin = tid*8 + k; sh_kneed = KK - cum; break; }
            cum += hh[k];
        }
    }
    __syncthreads();
    const int n = sh_n;

    uint Tbits = 1u;
    if (n >= KK){
        const int bstar = sh_bin, kneed = sh_kneed;
        #pragma unroll
        for (int ss = 0; ss < 4; ++ss){
            int s = wv*4 + ss;
            int c = segc[s];
            const float* ps = cs + (size_t)(b*64 + s) * TCAP;
            for (int i = lane; i < c; i += 64){
                float v = ps[i];
                if ((int)fxbin(v) == bstar){
                    int p = atomicAdd(&bcnt, 1);
                    if (p < SELCAP) keys[p] = (u64)__float_as_uint(v);
                }
            }
        }
        __syncthreads();
        int m = bcnt; if (m > SELCAP) m = SELCAP;
        if (tid < m){
            u64 mine = keys[tid];
            int gt = 0, ge = 0;
            for (int j = 0; j < m; ++j){
                u64 v = keys[j];
                gt += (v > mine) ? 1 : 0;
                ge += (v >= mine) ? 1 : 0;
            }
            if (gt < kneed && kneed <= ge) sh_Tbits = (uint)mine;
        }
        __syncthreads();
        Tbits = sh_Tbits;
    }

    #pragma unroll
    for (int ss = 0; ss < 4; ++ss){
        int s = wv*4 + ss;
        int c = segc[s];
        const float* ps = cs + (size_t)(b*64 + s) * TCAP;
        const int*   pi = ci + (size_t)(b*64 + s) * TCAP;
        for (int i0 = 0; i0 < c; i0 += 64){
            int i = i0 + lane;
            bool hit = false; uint bits = 0;
            if (i < c){ bits = __float_as_uint(ps[i]); hit = (bits >= Tbits); }
            u64 m = __ballot(hit);
            if (!m) continue;
            int wbase = 0;
            if (lane == 0) wbase = atomicAdd(&selCnt, (int)__popcll(m));
            wbase = __shfl(wbase, 0);
            if (hit){
                int p = wbase + (int)__popcll(m & ((1ull << lane) - 1ull));
                if (p < SELCAP) keys[p] = ((u64)bits << 32) | (uint)(~pi[i]);
            }
        }
    }
    __syncthreads();
    int ns = selCnt; if (ns > SELCAP) ns = SELCAP;
    for (int i = ns + tid; i < NPADK; i += NT) keys[i] = 0ull;
    __syncthreads();

    if (ns <= NPADK){
        u64 ck[8];
        #pragma unroll
        for (int r = 0; r < 8; ++r) ck[r] = keys[r*64 + lane];
        for (int t0 = 0; t0 < 32; ++t0){
            int t = wv*32 + t0;
            u64 my = keys[t];
            int c = 0;
            #pragma unroll
            for (int r = 0; r < 8; ++r) c += (ck[r] > my) ? 1 : 0;
            #pragma unroll
            for (int off = 1; off < 64; off <<= 1) c += __shfl_xor(c, off);
            if (lane == 0 && my != 0ull && c < KK)
                sidx[c] = (int)(~(uint)(my & 0xFFFFFFFFull));
        }
    } else {
        for (int i = tid; i < ns; i += NT){
            u64 my = keys[i];
            int rank = 0;
            for (int j = 0; j < ns; ++j) rank += (keys[j] > my) ? 1 : 0;
            if (rank < KK) sidx[rank] = (int)(~(uint)(my & 0xFFFFFFFFull));
        }
    }
    __syncthreads();

    if (ns < KK && tid == 0){
        int fill = ns;
        for (int idx = 0; idx < HWW && fill < KK; ++idx){
            bool inCand = false;
            for (int s = 0; s < 64 && !inCand; ++s){
                const int* pi = ci + (size_t)(b*64 + s) * TCAP;
                int c = segc[s];
                for (int i = 0; i < c; ++i) if (pi[i] == idx){ inCand = true; break; }
            }
            if (!inCand) sidx[fill++] = idx;
        }
    }
    __syncthreads();

    if (slice == 0){
        const float* pb = pts + (size_t)b * 4 * HWW;
        float* out0 = out + (size_t)b * KK * 4;
        float* out2 = out + (size_t)(BB * KK * 4 + BB * CC * KK) + (size_t)b * KK * 2;
        for (int k = tid; k < KK; k += NT){
            int idx = sidx[k];
            out0[k * 4 + 0] = pb[idx];
            out0[k * 4 + 1] = pb[HWW + idx];
            out0[k * 4 + 2] = 0.0f;
            out0[k * 4 + 3] = 1.0f;
            out2[k * 2 + 0] = (float)(idx >> 9);
            out2[k * 2 + 1] = (float)(idx & (WW - 1));
        }
    }
    {
        int j = slice * NT + tid;
        int c = j >> 9;
        int k = j & (KK - 1);
        float* out1 = out + (size_t)(BB * KK * 4) + (size_t)b * CC * KK;
        out1[j] = feat[(size_t)b * CC * HWW + (size_t)c * HWW + sidx[k]];
    }
}

extern "C" void kernel_launch(void* const* d_in, const int* in_sizes, int n_in,
                              void* d_out, int out_size, void* d_ws, size_t ws_size,
                              hipStream_t stream) {
    const float* s    = (const float*)d_in[0];
    const float* feat = (const float*)d_in[1];
    const float* pts  = (const float*)d_in[2];
    float* out = (float*)d_out;

    char* w = (char*)d_ws;
    float* cs  = (float*)w;  w += (size_t)BB * 64 * TCAP * 4;
    int*   ci  = (int*)w;    w += (size_t)BB * 64 * TCAP * 4;
    int*   cnt = (int*)w;    w += (size_t)BB * 64 * 4;

    nms_fused_k<<<BB * 64, NT, 0, stream>>>(s, cs, ci, cnt);
    selgather_k<<<BB * 64, NT, 0, stream>>>(cs, ci, cnt, pts, feat, out);
}